// Round 9
// baseline (1694.976 us; speedup 1.0000x reference)
//
#include <hip/hip_runtime.h>
#include <hip/hip_bf16.h>
#include <stdint.h>
#include <stddef.h>

#define T_LEN 512
#define B_SZ  256
#define I_SZ  256
#define H_SZ  1024
#define NGRP  16   // blocks per barrier group (one batch-group)

typedef __attribute__((ext_vector_type(8))) short bf16x8;
typedef __attribute__((ext_vector_type(4))) float f32x4;
typedef __attribute__((ext_vector_type(4))) unsigned int u32x4;
typedef unsigned short u16;
typedef unsigned int   u32;
typedef unsigned long long u64;

__device__ inline u16 f2bf(float f) {
  union { float f; u32 u; } x; x.f = f;
  u32 r = x.u + 0x7fffu + ((x.u >> 16) & 1u);
  return (u16)(r >> 16);
}

// keep 8 bf16x8 values pinned in VGPRs (0 instructions)
#define PIN8(B, i) asm volatile("" : "+v"(B[i]), "+v"(B[i+1]), "+v"(B[i+2]), \
    "+v"(B[i+3]), "+v"(B[i+4]), "+v"(B[i+5]), "+v"(B[i+6]), "+v"(B[i+7]))
#define PIN32(B) do { PIN8(B,0); PIN8(B,8); PIN8(B,16); PIN8(B,24); } while (0)

struct GCnt { u32 v; u32 pad[31]; };  // one 128B line per group counter

__global__ __launch_bounds__(256) void cvt_kernel(const float* __restrict__ src,
                                                  u16* __restrict__ dst, int n) {
  int stride = gridDim.x * blockDim.x * 4;
  for (int i = (blockIdx.x * blockDim.x + threadIdx.x) * 4; i < n; i += stride) {
    float4 v = *reinterpret_cast<const float4*>(src + i);
    ushort4 o;
    o.x = f2bf(v.x); o.y = f2bf(v.y); o.z = f2bf(v.z); o.w = f2bf(v.w);
    *reinterpret_cast<ushort4*>(dst + i) = o;
  }
}

// Persistent fused CTRNN (round-8 sync structure, proven; stage1 fused in).
// 256 blocks = 16 batch-groups x 16 col-groups. Per step per wave:
//   acc  = W_hh_frag (regs, K=1024) x h_frag (LDS, MALL-staged)     [32 MFMA]
//        + W_in_frag (regs, K=256)  x x_frag (LDS, staged 1 step ahead) [8 MFMA]
//   h    = 0.9*hprev + 0.1*relu(acc + b_in + b_hh)
// Sync: one __hip_atomic_fetch_add post per block after __syncthreads drains
// h-stores; only tid0 polls the padded group counter. All cross-block comms
// via proven __hip_atomic_* AGENT primitives + sc0 sc1 data loads (r6/r8).
__global__ __launch_bounds__(256, 1) void rnn_persistent(
    const float* __restrict__ x, const u16* __restrict__ Win,
    const u16* __restrict__ Whh, const float* __restrict__ b_in,
    const float* __restrict__ b_hh, float* __restrict__ out,
    u16* __restrict__ hb0, u16* __restrict__ hb1, GCnt* __restrict__ cnts) {
  __shared__ __align__(16) u16 As[16 * 1024];      // 32KB h tile, XOR-swizzled
  __shared__ __align__(16) u16 Xs[2][16 * 256];    // 2 x 8KB x tiles, swizzled

  const int b   = blockIdx.x;
  const int mg  = ((b & 7) << 1) | ((b >> 3) & 1);  // batch-group
  const int ng  = b >> 4;                           // col-group
  const int bm0 = mg * 16;
  const int bn0 = ng * 64;
  const int tid = threadIdx.x, lane = tid & 63, wid = tid >> 6;
  const int rl  = lane & 15, kq = lane >> 4;

  u32* cnt = &cnts[mg].v;

  // W fragments in registers: W_hh 16 cols x K=1024 (128 VGPR) + W_in K=256 (32)
  const int wcol = bn0 + wid * 16 + rl;
  bf16x8 Breg[32];
#pragma unroll
  for (int kc = 0; kc < 32; ++kc)
    Breg[kc] = *reinterpret_cast<const bf16x8*>(Whh + (size_t)wcol * H_SZ + kc * 32 + kq * 8);
  bf16x8 Wreg[8];
#pragma unroll
  for (int kc = 0; kc < 8; ++kc)
    Wreg[kc] = *reinterpret_cast<const bf16x8*>(Win + (size_t)wcol * I_SZ + kc * 32 + kq * 8);
  PIN32(Breg);
  PIN8(Wreg, 0);

  const int row = bm0 + rl;                  // batch row (D col dim)
  const int c0  = bn0 + wid * 16 + kq * 4;   // 4 consecutive hidden cols (D rows)
  float4 bsum;
#pragma unroll
  for (int r = 0; r < 4; ++r)
    (&bsum.x)[r] = b_in[c0 + r] + b_hh[c0 + r];

  float4 hprev = {0.f, 0.f, 0.f, 0.f};
  const char* Asb = (const char*)As;

  const int wb = (tid & 127) * 16;  // h-stage: in-row byte offset
  const int rb = tid >> 7;          // h-stage: row parity

  // x staging: thread handles 2 x 16B bf16 chunks of the 16x256 tile
  const int xc0 = tid * 2;

  // stage x tile for step s into Xs[s&1] (plain cached fp32 loads + cvt)
  auto stage_x = [&](int s) {
    const float* xs = x + (size_t)s * (B_SZ * I_SZ);
#pragma unroll
    for (int j = 0; j < 2; ++j) {
      int c  = xc0 + j;
      int r_ = c >> 5;               // row 0..15 (32 chunks per row)
      int cb = (c & 31) * 16;        // byte offset within 512B bf16 row
      const float* src = xs + (size_t)(bm0 + r_) * I_SZ + (c & 31) * 8;
      float4 f0 = *reinterpret_cast<const float4*>(src);
      float4 f1 = *reinterpret_cast<const float4*>(src + 4);
      u32x4 v;
      v.x = (u32)f2bf(f0.x) | ((u32)f2bf(f0.y) << 16);
      v.y = (u32)f2bf(f0.z) | ((u32)f2bf(f0.w) << 16);
      v.z = (u32)f2bf(f1.x) | ((u32)f2bf(f1.y) << 16);
      v.w = (u32)f2bf(f1.z) | ((u32)f2bf(f1.w) << 16);
      int dst = r_ * 512 + (cb ^ ((r_ & 7) << 4));   // XOR-swizzled
      *reinterpret_cast<u32x4*>((char*)Xs[s & 1] + dst) = v;
    }
  };

  stage_x(0);
  __syncthreads();

  for (int t = 0; t < T_LEN; ++t) {
    const u16* hin = (t & 1) ? hb1 : hb0;
    u16* hout      = (t & 1) ? hb0 : hb1;

    PIN32(Breg);

    // ---- stage h tile (16 x 1024 bf16): 8 x 16B MALL-coherent loads, one
    // wait, swizzled ds_write_b128 (r6/r8-proven data path)
    u32x4 sv[8];
    const char* hinb = (const char*)hin;
#pragma unroll
    for (int i = 0; i < 8; ++i) {
      int r_ = 2 * i + rb;
      const void* src = hinb + (size_t)(bm0 + r_) * 2048 + wb;
      asm volatile("global_load_dwordx4 %0, %1, off sc0 sc1"
                   : "=v"(sv[i]) : "v"(src) : "memory");
    }
    asm volatile("s_waitcnt vmcnt(0)" ::: "memory");
    __builtin_amdgcn_sched_barrier(0);
#pragma unroll
    for (int i = 0; i < 8; ++i) {
      int r_ = 2 * i + rb;
      int dst = r_ * 2048 + (wb ^ ((r_ & 7) << 4));
      *reinterpret_cast<u32x4*>((char*)As + dst) = sv[i];
    }
    __syncthreads();

    PIN32(Breg);

    // ---- MFMA: D = [W_hh | W_in] x [h | x]^T ; 3 independent acc chains
    f32x4 acc0 = (f32x4){0.f, 0.f, 0.f, 0.f};
    f32x4 acc1 = (f32x4){0.f, 0.f, 0.f, 0.f};
    f32x4 acc2 = (f32x4){0.f, 0.f, 0.f, 0.f};
#pragma unroll
    for (int kc = 0; kc < 32; kc += 2) {
      bf16x8 a0 = *reinterpret_cast<const bf16x8*>(
          Asb + rl * 2048 + ((kc * 64 + kq * 16) ^ ((rl & 7) << 4)));
      acc0 = __builtin_amdgcn_mfma_f32_16x16x32_bf16(Breg[kc], a0, acc0, 0, 0, 0);
      bf16x8 a1 = *reinterpret_cast<const bf16x8*>(
          Asb + rl * 2048 + (((kc + 1) * 64 + kq * 16) ^ ((rl & 7) << 4)));
      acc1 = __builtin_amdgcn_mfma_f32_16x16x32_bf16(Breg[kc + 1], a1, acc1, 0, 0, 0);
    }
    {
      const char* Xb = (const char*)Xs[t & 1];
#pragma unroll
      for (int kc = 0; kc < 8; ++kc) {
        bf16x8 xa = *reinterpret_cast<const bf16x8*>(
            Xb + rl * 512 + ((kc * 64 + kq * 16) ^ ((rl & 7) << 4)));
        acc2 = __builtin_amdgcn_mfma_f32_16x16x32_bf16(Wreg[kc], xa, acc2, 0, 0, 0);
      }
    }

    // ---- epilogue: compute h, store bf16 h (agent atomic)
    float hv[4];
#pragma unroll
    for (int r = 0; r < 4; ++r) {
      float pre = acc0[r] + acc1[r] + acc2[r] + (&bsum.x)[r];
      float hn  = fmaxf(pre, 0.f);
      float h   = (&hprev.x)[r] * 0.9f + hn * 0.1f;
      (&hprev.x)[r] = h;
      hv[r] = h;
    }
    u32 lo = (u32)f2bf(hv[0]) | ((u32)f2bf(hv[1]) << 16);
    u32 hi = (u32)f2bf(hv[2]) | ((u32)f2bf(hv[3]) << 16);
    u64 pk = (u64)lo | ((u64)hi << 32);
    __hip_atomic_store(reinterpret_cast<u64*>(hout + (size_t)row * H_SZ + c0), pk,
                       __ATOMIC_RELAXED, __HIP_MEMORY_SCOPE_AGENT);

    // ---- post: barrier drains every wave's vmcnt (h-stores acked), then one
    // fetch_add per block
    __syncthreads();
    if (t < T_LEN - 1 && tid == 0)
      __hip_atomic_fetch_add(cnt, 1u, __ATOMIC_RELAXED, __HIP_MEMORY_SCOPE_AGENT);

    // off-critical-path work overlaps the leader's poll:
    if (t < T_LEN - 1) stage_x(t + 1);          // x tile for next step
    float4 ho = {hv[0], hv[1], hv[2], hv[3]};
    *reinterpret_cast<float4*>(out + (size_t)t * (B_SZ * H_SZ) +
                               (size_t)row * H_SZ + c0) = ho;
    if (t == T_LEN - 1)
      *reinterpret_cast<float4*>(out + (size_t)T_LEN * (B_SZ * H_SZ) +
                                 (size_t)row * H_SZ + c0) = ho;

    // ---- leader poll: counter reaches NGRP*(t+1) when whole group posted
    if (t < T_LEN - 1) {
      if (tid == 0) {
        const u32 tgt = (u32)(NGRP * (t + 1));
        while (__hip_atomic_load(cnt, __ATOMIC_RELAXED, __HIP_MEMORY_SCOPE_AGENT) < tgt) {
        }
      }
      __syncthreads();
      __builtin_amdgcn_sched_barrier(0);
    }
  }
}

extern "C" void kernel_launch(void* const* d_in, const int* in_sizes, int n_in,
                              void* d_out, int out_size, void* d_ws, size_t ws_size,
                              hipStream_t stream) {
  const float* x    = (const float*)d_in[0];
  const float* W_in = (const float*)d_in[1];
  const float* b_in = (const float*)d_in[2];
  const float* W_hh = (const float*)d_in[3];
  const float* b_hh = (const float*)d_in[4];
  float* out = (float*)d_out;

  // workspace layout (bytes) — no overlaps, everything fits easily now
  const size_t off_wib = 0;             // 1024*256  bf16 = 524288
  const size_t off_whb = 524288;        // 1024*1024 bf16 = 2097152
  const size_t off_hb0 = 2621440;       // 256*1024  bf16 = 524288
  const size_t off_hb1 = 3145728;
  const size_t off_cnt = 3670016;       // 16 * 128B = 2048
  const size_t need    = 3672064;
  if (ws_size < need) return;

  char* ws = (char*)d_ws;
  u16* wib  = (u16*)(ws + off_wib);
  u16* whb  = (u16*)(ws + off_whb);
  u16* hb0  = (u16*)(ws + off_hb0);
  u16* hb1  = (u16*)(ws + off_hb1);
  GCnt* cnts = (GCnt*)(ws + off_cnt);

  cvt_kernel<<<64,  256, 0, stream>>>(W_in, wib, H_SZ * I_SZ);
  cvt_kernel<<<256, 256, 0, stream>>>(W_hh, whb, H_SZ * H_SZ);
  hipMemsetAsync(hb0, 0, (size_t)B_SZ * H_SZ * sizeof(u16), stream);
  hipMemsetAsync(cnts, 0, NGRP * sizeof(GCnt), stream);

  rnn_persistent<<<256, 256, 0, stream>>>(x, wib, whb, b_in, b_hh,
                                          out, hb0, hb1, cnts);
}

// Round 11
// 1272.919 us; speedup vs baseline: 1.3316x; 1.3316x over previous
//
#include <hip/hip_runtime.h>
#include <hip/hip_bf16.h>
#include <stdint.h>
#include <stddef.h>

#define T_LEN 512
#define B_SZ  256
#define I_SZ  256
#define H_SZ  1024
#define NGRP  16   // blocks per barrier group (one batch-group)

typedef __attribute__((ext_vector_type(8))) short bf16x8;
typedef __attribute__((ext_vector_type(4))) float f32x4;
typedef __attribute__((ext_vector_type(4))) unsigned int u32x4;
typedef unsigned short u16;
typedef unsigned int   u32;
typedef unsigned long long u64;

__device__ inline u16 f2bf(float f) {
  union { float f; u32 u; } x; x.f = f;
  u32 r = x.u + 0x7fffu + ((x.u >> 16) & 1u);
  return (u16)(r >> 16);
}
__device__ inline u32 bf2pk(u32 a, u32 b) {  // two fp32 bit-patterns -> packed bf16x2
  u32 ra = (a + 0x7fffu + ((a >> 16) & 1u)) >> 16;
  u32 rb = (b + 0x7fffu + ((b >> 16) & 1u)) >> 16;
  return ra | (rb << 16);
}

// keep 8 bf16x8 values pinned in VGPRs (0 instructions)
#define PIN8(B, i) asm volatile("" : "+v"(B[i]), "+v"(B[i+1]), "+v"(B[i+2]), \
    "+v"(B[i+3]), "+v"(B[i+4]), "+v"(B[i+5]), "+v"(B[i+6]), "+v"(B[i+7]))
#define PIN32(B) do { PIN8(B,0); PIN8(B,8); PIN8(B,16); PIN8(B,24); } while (0)

struct GCnt { u32 v; u32 pad[31]; };  // one 128B line per group counter

__global__ __launch_bounds__(256) void cvt_kernel(const float* __restrict__ src,
                                                  u16* __restrict__ dst, int n) {
  int stride = gridDim.x * blockDim.x * 4;
  for (int i = (blockIdx.x * blockDim.x + threadIdx.x) * 4; i < n; i += stride) {
    float4 v = *reinterpret_cast<const float4*>(src + i);
    ushort4 o;
    o.x = f2bf(v.x); o.y = f2bf(v.y); o.z = f2bf(v.z); o.w = f2bf(v.w);
    *reinterpret_cast<ushort4*>(dst + i) = o;
  }
}

// Persistent fused CTRNN. Exactly r9 (passing) plus ONE change: the x-tile
// loads for step t+1 are ISSUED right after the h-stage loads (land under the
// MFMA phase) and only cvt+ds_write remain in the post-shadow. Rule-18 fences:
// sched_barrier(0) after every inline-asm s_waitcnt whose data is consumed by
// register-only ops. Barriers are plain __syncthreads (r9-proven); LDS swizzle
// is the r3..r9-proven ^((r&7)<<4) on both write and read sides.
__global__ __launch_bounds__(256, 1) void rnn_persistent(
    const float* __restrict__ x, const u16* __restrict__ Win,
    const u16* __restrict__ Whh, const float* __restrict__ b_in,
    const float* __restrict__ b_hh, float* __restrict__ out,
    u16* __restrict__ hb0, u16* __restrict__ hb1, GCnt* __restrict__ cnts) {
  __shared__ __align__(16) u16 As[16 * 1024];      // 32KB h tile, swizzled
  __shared__ __align__(16) u16 Xs[2][16 * 256];    // 2 x 8KB x tiles, swizzled

  const int b   = blockIdx.x;
  const int mg  = ((b & 7) << 1) | ((b >> 3) & 1);  // batch-group
  const int ng  = b >> 4;                           // col-group
  const int bm0 = mg * 16;
  const int bn0 = ng * 64;
  const int tid = threadIdx.x, lane = tid & 63, wid = tid >> 6;
  const int rl  = lane & 15, kq = lane >> 4;

  u32* cnt = &cnts[mg].v;

  // W fragments in registers: W_hh 16 cols x K=1024 + W_in K=256
  const int wcol = bn0 + wid * 16 + rl;
  bf16x8 Breg[32];
#pragma unroll
  for (int kc = 0; kc < 32; ++kc)
    Breg[kc] = *reinterpret_cast<const bf16x8*>(Whh + (size_t)wcol * H_SZ + kc * 32 + kq * 8);
  bf16x8 Wreg[8];
#pragma unroll
  for (int kc = 0; kc < 8; ++kc)
    Wreg[kc] = *reinterpret_cast<const bf16x8*>(Win + (size_t)wcol * I_SZ + kc * 32 + kq * 8);
  PIN32(Breg);
  PIN8(Wreg, 0);

  const int row = bm0 + rl;                  // batch row (D col dim)
  const int c0  = bn0 + wid * 16 + kq * 4;   // 4 consecutive hidden cols (D rows)
  float4 bsum;
#pragma unroll
  for (int r = 0; r < 4; ++r)
    (&bsum.x)[r] = b_in[c0 + r] + b_hh[c0 + r];

  float4 hprev = {0.f, 0.f, 0.f, 0.f};
  const char* Asb = (const char*)As;

  const int wb = (tid & 127) * 16;  // h-stage: in-row byte offset
  const int rb = tid >> 7;          // h-stage: row parity

  // x tile geometry: chunk c = tid*2+j ; row r_=c>>5 ; in-row byte cb=(c&31)*16
  const int xc0 = tid * 2;

  // prologue: stage x tile for step 0 (plain compiler-visible loads)
  {
    const float* xs = x;
#pragma unroll
    for (int j = 0; j < 2; ++j) {
      int c  = xc0 + j;
      int r_ = c >> 5;
      int cb = (c & 31) * 16;
      const float* src = xs + (size_t)(bm0 + r_) * I_SZ + (c & 31) * 8;
      float4 f0 = *reinterpret_cast<const float4*>(src);
      float4 f1 = *reinterpret_cast<const float4*>(src + 4);
      u32x4 v;
      v.x = (u32)f2bf(f0.x) | ((u32)f2bf(f0.y) << 16);
      v.y = (u32)f2bf(f0.z) | ((u32)f2bf(f0.w) << 16);
      v.z = (u32)f2bf(f1.x) | ((u32)f2bf(f1.y) << 16);
      v.w = (u32)f2bf(f1.z) | ((u32)f2bf(f1.w) << 16);
      int dst = r_ * 512 + (cb ^ ((r_ & 7) << 4));
      *reinterpret_cast<u32x4*>((char*)Xs[0] + dst) = v;
    }
  }
  __syncthreads();

  for (int t = 0; t < T_LEN; ++t) {
    const u16* hin = (t & 1) ? hb1 : hb0;
    u16* hout      = (t & 1) ? hb0 : hb1;

    PIN32(Breg);

    // ---- stage h tile: 8 x 16B MALL-coherent loads
    u32x4 sv[8];
    const char* hinb = (const char*)hin;
#pragma unroll
    for (int i = 0; i < 8; ++i) {
      int r_ = 2 * i + rb;
      const void* src = hinb + (size_t)(bm0 + r_) * 2048 + wb;
      asm volatile("global_load_dwordx4 %0, %1, off sc0 sc1"
                   : "=v"(sv[i]) : "v"(src) : "memory");
    }
    // ---- issue x loads for t+1 now (plain cached); they land under MFMA
    u32x4 xv[4];
    if (t < T_LEN - 1) {
      const float* xs = x + (size_t)(t + 1) * (B_SZ * I_SZ);
#pragma unroll
      for (int j = 0; j < 2; ++j) {
        int c = xc0 + j;
        int r_ = c >> 5;
        const void* src = xs + (size_t)(bm0 + r_) * I_SZ + (c & 31) * 8;
        asm volatile("global_load_dwordx4 %0, %1, off"
                     : "=v"(xv[2 * j]) : "v"(src) : "memory");
        asm volatile("global_load_dwordx4 %0, %1, off offset:16"
                     : "=v"(xv[2 * j + 1]) : "v"(src) : "memory");
      }
      asm volatile("s_waitcnt vmcnt(4)" ::: "memory");  // h done (FIFO), x in flight
    } else {
      asm volatile("s_waitcnt vmcnt(0)" ::: "memory");
    }
    __builtin_amdgcn_sched_barrier(0);   // rule-18: nothing crosses the waitcnt
#pragma unroll
    for (int i = 0; i < 8; ++i) {
      int r_ = 2 * i + rb;
      int dst = r_ * 2048 + (wb ^ ((r_ & 7) << 4));   // proven swizzle
      *reinterpret_cast<u32x4*>((char*)As + dst) = sv[i];
    }
    __syncthreads();   // full barrier (r9-proven); drains x loads too (they land ~with h)

    PIN32(Breg);

    // ---- MFMA: D = [W_hh | W_in] x [h | x]^T
    f32x4 acc0 = (f32x4){0.f, 0.f, 0.f, 0.f};
    f32x4 acc1 = (f32x4){0.f, 0.f, 0.f, 0.f};
    f32x4 acc2 = (f32x4){0.f, 0.f, 0.f, 0.f};
#pragma unroll
    for (int kc = 0; kc < 32; kc += 2) {
      bf16x8 a0 = *reinterpret_cast<const bf16x8*>(
          Asb + rl * 2048 + ((kc * 64 + kq * 16) ^ ((rl & 7) << 4)));
      acc0 = __builtin_amdgcn_mfma_f32_16x16x32_bf16(Breg[kc], a0, acc0, 0, 0, 0);
      bf16x8 a1 = *reinterpret_cast<const bf16x8*>(
          Asb + rl * 2048 + (((kc + 1) * 64 + kq * 16) ^ ((rl & 7) << 4)));
      acc1 = __builtin_amdgcn_mfma_f32_16x16x32_bf16(Breg[kc + 1], a1, acc1, 0, 0, 0);
    }
    {
      const char* Xb = (const char*)Xs[t & 1];
#pragma unroll
      for (int kc = 0; kc < 8; ++kc) {
        bf16x8 xa = *reinterpret_cast<const bf16x8*>(
            Xb + rl * 512 + ((kc * 64 + kq * 16) ^ ((rl & 7) << 4)));
        acc2 = __builtin_amdgcn_mfma_f32_16x16x32_bf16(Wreg[kc], xa, acc2, 0, 0, 0);
      }
    }

    // ---- epilogue: compute h, store bf16 h (agent atomic)
    float hv[4];
#pragma unroll
    for (int r = 0; r < 4; ++r) {
      float pre = acc0[r] + acc1[r] + acc2[r] + (&bsum.x)[r];
      float hn  = fmaxf(pre, 0.f);
      float h   = (&hprev.x)[r] * 0.9f + hn * 0.1f;
      (&hprev.x)[r] = h;
      hv[r] = h;
    }
    u32 lo = (u32)f2bf(hv[0]) | ((u32)f2bf(hv[1]) << 16);
    u32 hi = (u32)f2bf(hv[2]) | ((u32)f2bf(hv[3]) << 16);
    u64 pk = (u64)lo | ((u64)hi << 32);
    __hip_atomic_store(reinterpret_cast<u64*>(hout + (size_t)row * H_SZ + c0), pk,
                       __ATOMIC_RELAXED, __HIP_MEMORY_SCOPE_AGENT);

    // ---- post: __syncthreads drains every wave's vmcnt (h-store acked),
    // then one fetch_add per block
    __syncthreads();
    if (t < T_LEN - 1 && tid == 0)
      __hip_atomic_fetch_add(cnt, 1u, __ATOMIC_RELAXED, __HIP_MEMORY_SCOPE_AGENT);

    // ---- post-shadow: x cvt + Xs write (loads landed long ago), out stores
    if (t < T_LEN - 1) {
      asm volatile("s_waitcnt vmcnt(0)" ::: "memory");
      __builtin_amdgcn_sched_barrier(0);   // rule-18: xv uses stay after waitcnt
      char* Xw = (char*)Xs[(t + 1) & 1];
#pragma unroll
      for (int j = 0; j < 2; ++j) {
        int c  = xc0 + j;
        int r_ = c >> 5;
        int cb = (c & 31) * 16;
        u32x4 f0 = xv[2 * j], f1 = xv[2 * j + 1];
        u32x4 v;
        v.x = bf2pk(f0.x, f0.y);
        v.y = bf2pk(f0.z, f0.w);
        v.z = bf2pk(f1.x, f1.y);
        v.w = bf2pk(f1.z, f1.w);
        int dst = r_ * 512 + (cb ^ ((r_ & 7) << 4));
        *reinterpret_cast<u32x4*>(Xw + dst) = v;
      }
    }
    float4 ho = {hv[0], hv[1], hv[2], hv[3]};
    *reinterpret_cast<float4*>(out + (size_t)t * (B_SZ * H_SZ) +
                               (size_t)row * H_SZ + c0) = ho;
    if (t == T_LEN - 1)
      *reinterpret_cast<float4*>(out + (size_t)T_LEN * (B_SZ * H_SZ) +
                                 (size_t)row * H_SZ + c0) = ho;

    // ---- leader poll, then release (__syncthreads also makes Xs visible)
    if (t < T_LEN - 1) {
      if (tid == 0) {
        const u32 tgt = (u32)(NGRP * (t + 1));
        while (__hip_atomic_load(cnt, __ATOMIC_RELAXED, __HIP_MEMORY_SCOPE_AGENT) < tgt) {
        }
      }
      __syncthreads();
      __builtin_amdgcn_sched_barrier(0);
    }
  }
}

extern "C" void kernel_launch(void* const* d_in, const int* in_sizes, int n_in,
                              void* d_out, int out_size, void* d_ws, size_t ws_size,
                              hipStream_t stream) {
  const float* x    = (const float*)d_in[0];
  const float* W_in = (const float*)d_in[1];
  const float* b_in = (const float*)d_in[2];
  const float* W_hh = (const float*)d_in[3];
  const float* b_hh = (const float*)d_in[4];
  float* out = (float*)d_out;

  // workspace layout (bytes) — no overlaps
  const size_t off_wib = 0;             // 1024*256  bf16 = 524288
  const size_t off_whb = 524288;        // 1024*1024 bf16 = 2097152
  const size_t off_hb0 = 2621440;       // 256*1024  bf16 = 524288
  const size_t off_hb1 = 3145728;
  const size_t off_cnt = 3670016;       // 16 * 128B = 2048
  const size_t need    = 3672064;
  if (ws_size < need) return;

  char* ws = (char*)d_ws;
  u16* wib  = (u16*)(ws + off_wib);
  u16* whb  = (u16*)(ws + off_whb);
  u16* hb0  = (u16*)(ws + off_hb0);
  u16* hb1  = (u16*)(ws + off_hb1);
  GCnt* cnts = (GCnt*)(ws + off_cnt);

  cvt_kernel<<<64,  256, 0, stream>>>(W_in, wib, H_SZ * I_SZ);
  cvt_kernel<<<256, 256, 0, stream>>>(W_hh, whb, H_SZ * H_SZ);
  hipMemsetAsync(hb0, 0, (size_t)B_SZ * H_SZ * sizeof(u16), stream);
  hipMemsetAsync(cnts, 0, NGRP * sizeof(GCnt), stream);

  rnn_persistent<<<256, 256, 0, stream>>>(x, wib, whb, b_in, b_hh,
                                          out, hb0, hb1, cnts);
}

// Round 12
// 1208.742 us; speedup vs baseline: 1.4023x; 1.0531x over previous
//
#include <hip/hip_runtime.h>
#include <hip/hip_bf16.h>
#include <stdint.h>
#include <stddef.h>

#define T_LEN 512
#define B_SZ  256
#define I_SZ  256
#define H_SZ  1024
#define NGRP  16   // blocks per barrier group (one batch-group)

typedef __attribute__((ext_vector_type(8))) short bf16x8;
typedef __attribute__((ext_vector_type(4))) float f32x4;
typedef __attribute__((ext_vector_type(4))) unsigned int u32x4;
typedef unsigned short u16;
typedef unsigned int   u32;
typedef unsigned long long u64;

__device__ inline u16 f2bf(float f) {
  union { float f; u32 u; } x; x.f = f;
  u32 r = x.u + 0x7fffu + ((x.u >> 16) & 1u);
  return (u16)(r >> 16);
}
__device__ inline u32 bf2pk(u32 a, u32 b) {  // two fp32 bit-patterns -> packed bf16x2
  u32 ra = (a + 0x7fffu + ((a >> 16) & 1u)) >> 16;
  u32 rb = (b + 0x7fffu + ((b >> 16) & 1u)) >> 16;
  return ra | (rb << 16);
}

// keep 8 bf16x8 values pinned in VGPRs (0 instructions)
#define PIN8(B, i) asm volatile("" : "+v"(B[i]), "+v"(B[i+1]), "+v"(B[i+2]), \
    "+v"(B[i+3]), "+v"(B[i+4]), "+v"(B[i+5]), "+v"(B[i+6]), "+v"(B[i+7]))
#define PIN32(B) do { PIN8(B,0); PIN8(B,8); PIN8(B,16); PIN8(B,24); } while (0)

struct GCnt { u32 v; u32 pad[31]; };  // one 128B line per group counter

__global__ __launch_bounds__(256) void cvt_kernel(const float* __restrict__ src,
                                                  u16* __restrict__ dst, int n) {
  int stride = gridDim.x * blockDim.x * 4;
  for (int i = (blockIdx.x * blockDim.x + threadIdx.x) * 4; i < n; i += stride) {
    float4 v = *reinterpret_cast<const float4*>(src + i);
    ushort4 o;
    o.x = f2bf(v.x); o.y = f2bf(v.y); o.z = f2bf(v.z); o.w = f2bf(v.w);
    *reinterpret_cast<ushort4*>(dst + i) = o;
  }
}

// Persistent fused CTRNN. Exactly r11 (passing, 1273us) plus ONE change:
// the x-tile MFMA chain (acc2) moves INTO the h-load flight window (it only
// depends on Xs[t&1], valid since last step's release barrier). The "memory"
// clobbers on the load asm pin the Xs ds_reads after all load issues; the
// sched_barrier(0) at the waitcnt keeps the acc2 MFMAs above the As writes.
__global__ __launch_bounds__(256, 1) void rnn_persistent(
    const float* __restrict__ x, const u16* __restrict__ Win,
    const u16* __restrict__ Whh, const float* __restrict__ b_in,
    const float* __restrict__ b_hh, float* __restrict__ out,
    u16* __restrict__ hb0, u16* __restrict__ hb1, GCnt* __restrict__ cnts) {
  __shared__ __align__(16) u16 As[16 * 1024];      // 32KB h tile, swizzled
  __shared__ __align__(16) u16 Xs[2][16 * 256];    // 2 x 8KB x tiles, swizzled

  const int b   = blockIdx.x;
  const int mg  = ((b & 7) << 1) | ((b >> 3) & 1);  // batch-group
  const int ng  = b >> 4;                           // col-group
  const int bm0 = mg * 16;
  const int bn0 = ng * 64;
  const int tid = threadIdx.x, lane = tid & 63, wid = tid >> 6;
  const int rl  = lane & 15, kq = lane >> 4;

  u32* cnt = &cnts[mg].v;

  // W fragments in registers: W_hh 16 cols x K=1024 + W_in K=256
  const int wcol = bn0 + wid * 16 + rl;
  bf16x8 Breg[32];
#pragma unroll
  for (int kc = 0; kc < 32; ++kc)
    Breg[kc] = *reinterpret_cast<const bf16x8*>(Whh + (size_t)wcol * H_SZ + kc * 32 + kq * 8);
  bf16x8 Wreg[8];
#pragma unroll
  for (int kc = 0; kc < 8; ++kc)
    Wreg[kc] = *reinterpret_cast<const bf16x8*>(Win + (size_t)wcol * I_SZ + kc * 32 + kq * 8);
  PIN32(Breg);
  PIN8(Wreg, 0);

  const int row = bm0 + rl;                  // batch row (D col dim)
  const int c0  = bn0 + wid * 16 + kq * 4;   // 4 consecutive hidden cols (D rows)
  float4 bsum;
#pragma unroll
  for (int r = 0; r < 4; ++r)
    (&bsum.x)[r] = b_in[c0 + r] + b_hh[c0 + r];

  float4 hprev = {0.f, 0.f, 0.f, 0.f};
  const char* Asb = (const char*)As;

  const int wb = (tid & 127) * 16;  // h-stage: in-row byte offset
  const int rb = tid >> 7;          // h-stage: row parity

  // x tile geometry: chunk c = tid*2+j ; row r_=c>>5 ; in-row byte cb=(c&31)*16
  const int xc0 = tid * 2;

  // prologue: stage x tile for step 0 (plain compiler-visible loads)
  {
    const float* xs = x;
#pragma unroll
    for (int j = 0; j < 2; ++j) {
      int c  = xc0 + j;
      int r_ = c >> 5;
      int cb = (c & 31) * 16;
      const float* src = xs + (size_t)(bm0 + r_) * I_SZ + (c & 31) * 8;
      float4 f0 = *reinterpret_cast<const float4*>(src);
      float4 f1 = *reinterpret_cast<const float4*>(src + 4);
      u32x4 v;
      v.x = (u32)f2bf(f0.x) | ((u32)f2bf(f0.y) << 16);
      v.y = (u32)f2bf(f0.z) | ((u32)f2bf(f0.w) << 16);
      v.z = (u32)f2bf(f1.x) | ((u32)f2bf(f1.y) << 16);
      v.w = (u32)f2bf(f1.z) | ((u32)f2bf(f1.w) << 16);
      int dst = r_ * 512 + (cb ^ ((r_ & 7) << 4));
      *reinterpret_cast<u32x4*>((char*)Xs[0] + dst) = v;
    }
  }
  __syncthreads();

  for (int t = 0; t < T_LEN; ++t) {
    const u16* hin = (t & 1) ? hb1 : hb0;
    u16* hout      = (t & 1) ? hb0 : hb1;

    PIN32(Breg);

    // ---- stage h tile: 8 x 16B MALL-coherent loads
    u32x4 sv[8];
    const char* hinb = (const char*)hin;
#pragma unroll
    for (int i = 0; i < 8; ++i) {
      int r_ = 2 * i + rb;
      const void* src = hinb + (size_t)(bm0 + r_) * 2048 + wb;
      asm volatile("global_load_dwordx4 %0, %1, off sc0 sc1"
                   : "=v"(sv[i]) : "v"(src) : "memory");
    }
    // ---- issue x loads for t+1 now (plain cached); they land under MFMA
    u32x4 xv[4];
    if (t < T_LEN - 1) {
      const float* xs = x + (size_t)(t + 1) * (B_SZ * I_SZ);
#pragma unroll
      for (int j = 0; j < 2; ++j) {
        int c = xc0 + j;
        int r_ = c >> 5;
        const void* src = xs + (size_t)(bm0 + r_) * I_SZ + (c & 31) * 8;
        asm volatile("global_load_dwordx4 %0, %1, off"
                     : "=v"(xv[2 * j]) : "v"(src) : "memory");
        asm volatile("global_load_dwordx4 %0, %1, off offset:16"
                     : "=v"(xv[2 * j + 1]) : "v"(src) : "memory");
      }
    }

    // ---- acc2 (x-tile MFMA) computes IN the h-load flight window: it reads
    // only Xs[t&1] (valid since last step's release barrier), no h dependence.
    f32x4 acc2 = (f32x4){0.f, 0.f, 0.f, 0.f};
    {
      const char* Xb = (const char*)Xs[t & 1];
#pragma unroll
      for (int kc = 0; kc < 8; ++kc) {
        bf16x8 xa = *reinterpret_cast<const bf16x8*>(
            Xb + rl * 512 + ((kc * 64 + kq * 16) ^ ((rl & 7) << 4)));
        acc2 = __builtin_amdgcn_mfma_f32_16x16x32_bf16(Wreg[kc], xa, acc2, 0, 0, 0);
      }
    }

    if (t < T_LEN - 1) {
      asm volatile("s_waitcnt vmcnt(4)" ::: "memory");  // h done (FIFO), x in flight
    } else {
      asm volatile("s_waitcnt vmcnt(0)" ::: "memory");
    }
    __builtin_amdgcn_sched_barrier(0);   // rule-18: nothing crosses the waitcnt
#pragma unroll
    for (int i = 0; i < 8; ++i) {
      int r_ = 2 * i + rb;
      int dst = r_ * 2048 + (wb ^ ((r_ & 7) << 4));   // proven swizzle
      *reinterpret_cast<u32x4*>((char*)As + dst) = sv[i];
    }
    __syncthreads();   // full barrier (r9/r11-proven)

    PIN32(Breg);

    // ---- MFMA: D = W_hh x h^T (acc2 already done)
    f32x4 acc0 = (f32x4){0.f, 0.f, 0.f, 0.f};
    f32x4 acc1 = (f32x4){0.f, 0.f, 0.f, 0.f};
#pragma unroll
    for (int kc = 0; kc < 32; kc += 2) {
      bf16x8 a0 = *reinterpret_cast<const bf16x8*>(
          Asb + rl * 2048 + ((kc * 64 + kq * 16) ^ ((rl & 7) << 4)));
      acc0 = __builtin_amdgcn_mfma_f32_16x16x32_bf16(Breg[kc], a0, acc0, 0, 0, 0);
      bf16x8 a1 = *reinterpret_cast<const bf16x8*>(
          Asb + rl * 2048 + (((kc + 1) * 64 + kq * 16) ^ ((rl & 7) << 4)));
      acc1 = __builtin_amdgcn_mfma_f32_16x16x32_bf16(Breg[kc + 1], a1, acc1, 0, 0, 0);
    }

    // ---- epilogue: compute h, store bf16 h (agent atomic)
    float hv[4];
#pragma unroll
    for (int r = 0; r < 4; ++r) {
      float pre = acc0[r] + acc1[r] + acc2[r] + (&bsum.x)[r];
      float hn  = fmaxf(pre, 0.f);
      float h   = (&hprev.x)[r] * 0.9f + hn * 0.1f;
      (&hprev.x)[r] = h;
      hv[r] = h;
    }
    u32 lo = (u32)f2bf(hv[0]) | ((u32)f2bf(hv[1]) << 16);
    u32 hi = (u32)f2bf(hv[2]) | ((u32)f2bf(hv[3]) << 16);
    u64 pk = (u64)lo | ((u64)hi << 32);
    __hip_atomic_store(reinterpret_cast<u64*>(hout + (size_t)row * H_SZ + c0), pk,
                       __ATOMIC_RELAXED, __HIP_MEMORY_SCOPE_AGENT);

    // ---- post: __syncthreads drains every wave's vmcnt (h-store acked),
    // then one fetch_add per block
    __syncthreads();
    if (t < T_LEN - 1 && tid == 0)
      __hip_atomic_fetch_add(cnt, 1u, __ATOMIC_RELAXED, __HIP_MEMORY_SCOPE_AGENT);

    // ---- post-shadow: x cvt + Xs write (loads landed long ago), out stores
    if (t < T_LEN - 1) {
      asm volatile("s_waitcnt vmcnt(0)" ::: "memory");
      __builtin_amdgcn_sched_barrier(0);   // rule-18: xv uses stay after waitcnt
      char* Xw = (char*)Xs[(t + 1) & 1];
#pragma unroll
      for (int j = 0; j < 2; ++j) {
        int c  = xc0 + j;
        int r_ = c >> 5;
        int cb = (c & 31) * 16;
        u32x4 f0 = xv[2 * j], f1 = xv[2 * j + 1];
        u32x4 v;
        v.x = bf2pk(f0.x, f0.y);
        v.y = bf2pk(f0.z, f0.w);
        v.z = bf2pk(f1.x, f1.y);
        v.w = bf2pk(f1.z, f1.w);
        int dst = r_ * 512 + (cb ^ ((r_ & 7) << 4));
        *reinterpret_cast<u32x4*>(Xw + dst) = v;
      }
    }
    float4 ho = {hv[0], hv[1], hv[2], hv[3]};
    *reinterpret_cast<float4*>(out + (size_t)t * (B_SZ * H_SZ) +
                               (size_t)row * H_SZ + c0) = ho;
    if (t == T_LEN - 1)
      *reinterpret_cast<float4*>(out + (size_t)T_LEN * (B_SZ * H_SZ) +
                                 (size_t)row * H_SZ + c0) = ho;

    // ---- leader poll, then release (__syncthreads also makes Xs visible)
    if (t < T_LEN - 1) {
      if (tid == 0) {
        const u32 tgt = (u32)(NGRP * (t + 1));
        while (__hip_atomic_load(cnt, __ATOMIC_RELAXED, __HIP_MEMORY_SCOPE_AGENT) < tgt) {
        }
      }
      __syncthreads();
      __builtin_amdgcn_sched_barrier(0);
    }
  }
}

extern "C" void kernel_launch(void* const* d_in, const int* in_sizes, int n_in,
                              void* d_out, int out_size, void* d_ws, size_t ws_size,
                              hipStream_t stream) {
  const float* x    = (const float*)d_in[0];
  const float* W_in = (const float*)d_in[1];
  const float* b_in = (const float*)d_in[2];
  const float* W_hh = (const float*)d_in[3];
  const float* b_hh = (const float*)d_in[4];
  float* out = (float*)d_out;

  // workspace layout (bytes) — no overlaps
  const size_t off_wib = 0;             // 1024*256  bf16 = 524288
  const size_t off_whb = 524288;        // 1024*1024 bf16 = 2097152
  const size_t off_hb0 = 2621440;       // 256*1024  bf16 = 524288
  const size_t off_hb1 = 3145728;
  const size_t off_cnt = 3670016;       // 16 * 128B = 2048
  const size_t need    = 3672064;
  if (ws_size < need) return;

  char* ws = (char*)d_ws;
  u16* wib  = (u16*)(ws + off_wib);
  u16* whb  = (u16*)(ws + off_whb);
  u16* hb0  = (u16*)(ws + off_hb0);
  u16* hb1  = (u16*)(ws + off_hb1);
  GCnt* cnts = (GCnt*)(ws + off_cnt);

  cvt_kernel<<<64,  256, 0, stream>>>(W_in, wib, H_SZ * I_SZ);
  cvt_kernel<<<256, 256, 0, stream>>>(W_hh, whb, H_SZ * H_SZ);
  hipMemsetAsync(hb0, 0, (size_t)B_SZ * H_SZ * sizeof(u16), stream);
  hipMemsetAsync(cnts, 0, NGRP * sizeof(GCnt), stream);

  rnn_persistent<<<256, 256, 0, stream>>>(x, wib, whb, b_in, b_hh,
                                          out, hb0, hb1, cnts);
}